// Round 1
// baseline (620.125 us; speedup 1.0000x reference)
//
#include <hip/hip_runtime.h>
#include <math.h>

#define B_ 32
#define C_ 256
#define HW_ 96
#define G_ 2
#define K_ 3
#define CR_ 64
#define IMG_ (HW_*HW_)       // 9216 floats per (b,c) image
#define BN_EPS 1e-5f

// ---------------------------------------------------------------------------
// Kernel 1: adaptive avg-pool to 3x3.  grid = B*C*3 (one WG per block-row),
// block = 256.  Coalesced float4 loads; 3 column-bin predicated accumulate;
// wave shuffle reduce + tiny LDS reduce.
// ---------------------------------------------------------------------------
__global__ __launch_bounds__(256) void pool_kernel(const float* __restrict__ x,
                                                   float* __restrict__ pooled) {
    int wg = blockIdx.x;
    int bh = wg % 3;          // block-row index (rows bh*32 .. bh*32+31)
    int bc = wg / 3;          // b*C + c
    const float4* src = (const float4*)(x + (size_t)bc * IMG_ + (size_t)bh * 32 * HW_);
    int t = threadIdx.x;
    float a0 = 0.f, a1 = 0.f, a2 = 0.f;
    #pragma unroll
    for (int k = 0; k < 3; ++k) {
        int f = t + 256 * k;               // float4 index in [0, 768)
        float4 v = src[f];
        float s = v.x + v.y + v.z + v.w;
        int colq = f % 24;                 // 24 float4s per row
        int bin = colq >> 3;               // 8 quads per 32-wide column block
        a0 += (bin == 0) ? s : 0.f;
        a1 += (bin == 1) ? s : 0.f;
        a2 += (bin == 2) ? s : 0.f;
    }
    #pragma unroll
    for (int off = 32; off > 0; off >>= 1) {
        a0 += __shfl_down(a0, off);
        a1 += __shfl_down(a1, off);
        a2 += __shfl_down(a2, off);
    }
    __shared__ float red[3][4];
    int wave = t >> 6, lane = t & 63;
    if (lane == 0) { red[0][wave] = a0; red[1][wave] = a1; red[2][wave] = a2; }
    __syncthreads();
    if (t < 3) {
        float s = red[t][0] + red[t][1] + red[t][2] + red[t][3];
        pooled[(size_t)bc * 9 + bh * 3 + t] = s * (1.0f / 1024.0f);  // 32*32 pixels
    }
}

// ---------------------------------------------------------------------------
// Kernel 2: projection MLP + softmax mixing.  grid = B (32), block = 256.
// pos in [0,10): 0..8 = the 3x3 pooled positions, 9 = global-avg-pool.
// Produces weight[B*C,9] and bias[B*C].
// ---------------------------------------------------------------------------
__global__ __launch_bounds__(256) void proj_kernel(
    const float* __restrict__ pooled,   // [B*C, 9]
    const float* __restrict__ dyn_w,    // [G, C, 9]
    const float* __restrict__ dyn_b,    // [G, C]
    const float* __restrict__ w1,       // [CR, C]
    const float* __restrict__ bn_g, const float* __restrict__ bn_b,
    const float* __restrict__ bn_m, const float* __restrict__ bn_v,
    const float* __restrict__ w2,       // [C*G, CR]
    const float* __restrict__ b2,       // [C*G]
    float* __restrict__ wout,           // [B*C, 9]
    float* __restrict__ bout)           // [B*C]
{
    int b = blockIdx.x;
    __shared__ float pool[C_][10];      // 40 KB
    __shared__ float hbuf[CR_][10];     // 2.5 KB
    int t = threadIdx.x;

    // load this sample's pooled features; pos 9 = gap = mean of the 9 means
    {
        const float* p = pooled + ((size_t)b * C_ + t) * 9;
        float s = 0.f;
        #pragma unroll
        for (int i = 0; i < 9; ++i) { float v = p[i]; pool[t][i] = v; s += v; }
        pool[t][9] = s * (1.0f / 9.0f);
    }
    __syncthreads();

    // h = w1 @ pool  -> BN -> exact GELU.   640 outputs (64 x 10).
    for (int task = t; task < CR_ * 10; task += 256) {
        int o = task & 63, pos = task >> 6;
        const float4* wr = (const float4*)(w1 + (size_t)o * C_);
        float acc = 0.f;
        #pragma unroll 8
        for (int i = 0; i < C_ / 4; ++i) {
            float4 wv = wr[i];
            acc += wv.x * pool[4*i][pos] + wv.y * pool[4*i+1][pos]
                 + wv.z * pool[4*i+2][pos] + wv.w * pool[4*i+3][pos];
        }
        float inv = bn_g[o] * rsqrtf(bn_v[o] + BN_EPS);
        float hv = acc * inv + (bn_b[o] - bn_m[o] * inv);
        hv = 0.5f * hv * (1.0f + erff(hv * 0.70710678118654752f));
        hbuf[o][pos] = hv;
    }
    __syncthreads();

    // s = w2 @ h + b2, softmax over G=2, mix dynamic banks.
    for (int task = t; task < C_ * 10; task += 256) {
        int c = task & 255, pos = task >> 8;
        const float4* r0 = (const float4*)(w2 + (size_t)c * CR_);          // n = c      (g=0)
        const float4* r1 = (const float4*)(w2 + (size_t)(C_ + c) * CR_);   // n = C + c  (g=1)
        float s0 = b2[c], s1 = b2[C_ + c];
        #pragma unroll 8
        for (int i = 0; i < CR_ / 4; ++i) {
            float4 v0 = r0[i], v1 = r1[i];
            float h0 = hbuf[4*i][pos], h1 = hbuf[4*i+1][pos];
            float h2 = hbuf[4*i+2][pos], h3 = hbuf[4*i+3][pos];
            s0 += v0.x*h0 + v0.y*h1 + v0.z*h2 + v0.w*h3;
            s1 += v1.x*h0 + v1.y*h1 + v1.z*h2 + v1.w*h3;
        }
        float m = fmaxf(s0, s1);
        float e0 = expf(s0 - m), e1 = expf(s1 - m);
        float p0 = e0 / (e0 + e1), p1 = 1.0f - p0;
        if (pos < 9) {
            wout[((size_t)b * C_ + c) * 9 + pos] =
                p0 * dyn_w[(size_t)c * 9 + pos] + p1 * dyn_w[(size_t)(C_ * 9) + c * 9 + pos];
        } else {
            bout[(size_t)b * C_ + c] = p0 * dyn_b[c] + p1 * dyn_b[C_ + c];
        }
    }
}

// ---------------------------------------------------------------------------
// Kernel 3: per-(b,c) depthwise 3x3 conv (pad 1) + bias.
// grid = B*C, block = 256.  98x98 zero-filled LDS tile (halo = padding).
// ---------------------------------------------------------------------------
#define TW 98
__global__ __launch_bounds__(256) void dwconv_kernel(const float* __restrict__ x,
                                                     const float* __restrict__ wgt,
                                                     const float* __restrict__ bias,
                                                     float* __restrict__ out) {
    int bc = blockIdx.x;
    __shared__ float tile[TW * TW];     // 38.4 KB -> 4 WG/CU
    int t = threadIdx.x;

    for (int i = t; i < TW * TW; i += 256) tile[i] = 0.f;
    __syncthreads();

    const float4* src = (const float4*)(x + (size_t)bc * IMG_);
    #pragma unroll
    for (int k = 0; k < 9; ++k) {
        int f = t + 256 * k;            // 2304 float4s per image
        float4 v = src[f];
        int r = f / 24, cq = f % 24;
        float* d = &tile[(r + 1) * TW + 1 + 4 * cq];
        d[0] = v.x; d[1] = v.y; d[2] = v.z; d[3] = v.w;
    }

    float w[9];
    #pragma unroll
    for (int i = 0; i < 9; ++i) w[i] = wgt[(size_t)bc * 9 + i];
    float bs = bias[bc];
    __syncthreads();

    float4* dst = (float4*)(out + (size_t)bc * IMG_);
    #pragma unroll
    for (int k = 0; k < 9; ++k) {
        int f = t + 256 * k;
        int r = f / 24, cq = f % 24;
        const float* base = &tile[r * TW + 4 * cq];   // input row r-1, col 4cq-1
        float a0 = bs, a1 = bs, a2 = bs, a3 = bs;
        #pragma unroll
        for (int dh = 0; dh < 3; ++dh) {
            const float* row = base + dh * TW;
            float i0 = row[0], i1 = row[1], i2 = row[2];
            float i3 = row[3], i4 = row[4], i5 = row[5];
            float w0 = w[dh*3], w1v = w[dh*3+1], w2v = w[dh*3+2];
            a0 += i0*w0 + i1*w1v + i2*w2v;
            a1 += i1*w0 + i2*w1v + i3*w2v;
            a2 += i2*w0 + i3*w1v + i4*w2v;
            a3 += i3*w0 + i4*w1v + i5*w2v;
        }
        dst[f] = make_float4(a0, a1, a2, a3);
    }
}

// ---------------------------------------------------------------------------
extern "C" void kernel_launch(void* const* d_in, const int* in_sizes, int n_in,
                              void* d_out, int out_size, void* d_ws, size_t ws_size,
                              hipStream_t stream) {
    const float* x     = (const float*)d_in[0];
    const float* dyn_w = (const float*)d_in[1];
    const float* dyn_b = (const float*)d_in[2];
    const float* w1    = (const float*)d_in[3];
    const float* bn_g  = (const float*)d_in[4];
    const float* bn_b  = (const float*)d_in[5];
    const float* bn_m  = (const float*)d_in[6];
    const float* bn_v  = (const float*)d_in[7];
    const float* w2    = (const float*)d_in[8];
    const float* b2    = (const float*)d_in[9];
    float* out = (float*)d_out;

    float* ws = (float*)d_ws;
    float* pooled = ws;                        // [B*C, 9]  = 73728 floats
    float* weight = ws + (size_t)B_ * C_ * 9;  // [B*C, 9]  = 73728 floats
    float* bias   = weight + (size_t)B_ * C_ * 9;  // [B*C] = 8192 floats

    pool_kernel<<<B_ * C_ * 3, 256, 0, stream>>>(x, pooled);
    proj_kernel<<<B_, 256, 0, stream>>>(pooled, dyn_w, dyn_b, w1, bn_g, bn_b,
                                        bn_m, bn_v, w2, b2, weight, bias);
    dwconv_kernel<<<B_ * C_, 256, 0, stream>>>(x, weight, bias, out);
}

// Round 2
// 618.930 us; speedup vs baseline: 1.0019x; 1.0019x over previous
//
#include <hip/hip_runtime.h>
#include <math.h>

#define B_ 32
#define C_ 256
#define HW_ 96
#define G_ 2
#define K_ 3
#define CR_ 64
#define IMG_ (HW_*HW_)       // 9216 floats per (b,c) image
#define BN_EPS 1e-5f

// ---------------------------------------------------------------------------
// Kernel 1: adaptive avg-pool to 3x3.  grid = B*C*3 (one WG per block-row),
// block = 256.  Coalesced float4 loads; 3 column-bin predicated accumulate;
// wave shuffle reduce + tiny LDS reduce.
// ---------------------------------------------------------------------------
__global__ __launch_bounds__(256) void pool_kernel(const float* __restrict__ x,
                                                   float* __restrict__ pooled) {
    int wg = blockIdx.x;
    int bh = wg % 3;          // block-row index (rows bh*32 .. bh*32+31)
    int bc = wg / 3;          // b*C + c
    const float4* src = (const float4*)(x + (size_t)bc * IMG_ + (size_t)bh * 32 * HW_);
    int t = threadIdx.x;
    float a0 = 0.f, a1 = 0.f, a2 = 0.f;
    #pragma unroll
    for (int k = 0; k < 3; ++k) {
        int f = t + 256 * k;               // float4 index in [0, 768)
        float4 v = src[f];
        float s = v.x + v.y + v.z + v.w;
        int colq = f % 24;                 // 24 float4s per row
        int bin = colq >> 3;               // 8 quads per 32-wide column block
        a0 += (bin == 0) ? s : 0.f;
        a1 += (bin == 1) ? s : 0.f;
        a2 += (bin == 2) ? s : 0.f;
    }
    #pragma unroll
    for (int off = 32; off > 0; off >>= 1) {
        a0 += __shfl_down(a0, off);
        a1 += __shfl_down(a1, off);
        a2 += __shfl_down(a2, off);
    }
    __shared__ float red[3][4];
    int wave = t >> 6, lane = t & 63;
    if (lane == 0) { red[0][wave] = a0; red[1][wave] = a1; red[2][wave] = a2; }
    __syncthreads();
    if (t < 3) {
        float s = red[t][0] + red[t][1] + red[t][2] + red[t][3];
        pooled[(size_t)bc * 9 + bh * 3 + t] = s * (1.0f / 1024.0f);  // 32*32 pixels
    }
}

// ---------------------------------------------------------------------------
// Kernel 2: projection MLP + softmax mixing.  grid = B (32), block = 256.
// pos in [0,10): 0..8 = the 3x3 pooled positions, 9 = global-avg-pool.
// Produces weight[B*C,9] and bias[B*C].
// ---------------------------------------------------------------------------
__global__ __launch_bounds__(256) void proj_kernel(
    const float* __restrict__ pooled,   // [B*C, 9]
    const float* __restrict__ dyn_w,    // [G, C, 9]
    const float* __restrict__ dyn_b,    // [G, C]
    const float* __restrict__ w1,       // [CR, C]
    const float* __restrict__ bn_g, const float* __restrict__ bn_b,
    const float* __restrict__ bn_m, const float* __restrict__ bn_v,
    const float* __restrict__ w2,       // [C*G, CR]
    const float* __restrict__ b2,       // [C*G]
    float* __restrict__ wout,           // [B*C, 9]
    float* __restrict__ bout)           // [B*C]
{
    int b = blockIdx.x;
    __shared__ float pool[C_][10];      // 40 KB
    __shared__ float hbuf[CR_][10];     // 2.5 KB
    int t = threadIdx.x;

    // load this sample's pooled features; pos 9 = gap = mean of the 9 means
    {
        const float* p = pooled + ((size_t)b * C_ + t) * 9;
        float s = 0.f;
        #pragma unroll
        for (int i = 0; i < 9; ++i) { float v = p[i]; pool[t][i] = v; s += v; }
        pool[t][9] = s * (1.0f / 9.0f);
    }
    __syncthreads();

    // h = w1 @ pool  -> BN -> exact GELU.   640 outputs (64 x 10).
    for (int task = t; task < CR_ * 10; task += 256) {
        int o = task & 63, pos = task >> 6;
        const float4* wr = (const float4*)(w1 + (size_t)o * C_);
        float acc = 0.f;
        #pragma unroll 8
        for (int i = 0; i < C_ / 4; ++i) {
            float4 wv = wr[i];
            acc += wv.x * pool[4*i][pos] + wv.y * pool[4*i+1][pos]
                 + wv.z * pool[4*i+2][pos] + wv.w * pool[4*i+3][pos];
        }
        float inv = bn_g[o] * rsqrtf(bn_v[o] + BN_EPS);
        float hv = acc * inv + (bn_b[o] - bn_m[o] * inv);
        hv = 0.5f * hv * (1.0f + erff(hv * 0.70710678118654752f));
        hbuf[o][pos] = hv;
    }
    __syncthreads();

    // s = w2 @ h + b2, softmax over G=2, mix dynamic banks.
    for (int task = t; task < C_ * 10; task += 256) {
        int c = task & 255, pos = task >> 8;
        const float4* r0 = (const float4*)(w2 + (size_t)c * CR_);          // n = c      (g=0)
        const float4* r1 = (const float4*)(w2 + (size_t)(C_ + c) * CR_);   // n = C + c  (g=1)
        float s0 = b2[c], s1 = b2[C_ + c];
        #pragma unroll 8
        for (int i = 0; i < CR_ / 4; ++i) {
            float4 v0 = r0[i], v1 = r1[i];
            float h0 = hbuf[4*i][pos], h1 = hbuf[4*i+1][pos];
            float h2 = hbuf[4*i+2][pos], h3 = hbuf[4*i+3][pos];
            s0 += v0.x*h0 + v0.y*h1 + v0.z*h2 + v0.w*h3;
            s1 += v1.x*h0 + v1.y*h1 + v1.z*h2 + v1.w*h3;
        }
        float m = fmaxf(s0, s1);
        float e0 = expf(s0 - m), e1 = expf(s1 - m);
        float p0 = e0 / (e0 + e1), p1 = 1.0f - p0;
        if (pos < 9) {
            wout[((size_t)b * C_ + c) * 9 + pos] =
                p0 * dyn_w[(size_t)c * 9 + pos] + p1 * dyn_w[(size_t)(C_ * 9) + c * 9 + pos];
        } else {
            bout[(size_t)b * C_ + c] = p0 * dyn_b[c] + p1 * dyn_b[C_ + c];
        }
    }
}

// ---------------------------------------------------------------------------
// Kernel 3: per-(b,c) depthwise 3x3 conv (pad 1) + bias.
// NO LDS: register sliding window.  grid = B*C, block = 192 (3 waves).
// Thread t owns quad-column qc = t%24 (output cols 4qc..4qc+3) and a
// 12-row strip (rg = t/24).  Per row: 1 aligned float4 load + 2 predicated
// edge scalars; 3x6 register window; coalesced float4 store.
// ---------------------------------------------------------------------------
__global__ __launch_bounds__(192) void dwconv_kernel(const float* __restrict__ x,
                                                     const float* __restrict__ wgt,
                                                     const float* __restrict__ bias,
                                                     float* __restrict__ out) {
    int bc = blockIdx.x;
    int t = threadIdx.x;
    int qc = t % 24;            // quad column 0..23
    int rg = t / 24;            // row group 0..7
    int r0 = rg * 12;

    const float* img = x + (size_t)bc * IMG_;
    float4* dst = (float4*)(out + (size_t)bc * IMG_);

    float w[9];
    #pragma unroll
    for (int i = 0; i < 9; ++i) w[i] = wgt[(size_t)bc * 9 + i];
    float bs = bias[bc];

    float A[6], Bv[6], Cv[6];   // rows r-1, r, r+1; cols 4qc-1 .. 4qc+4

    // loadrow: fills d[0..5] with img[r][4qc-1 .. 4qc+4] (zeros outside)
    #define LOADROW(r, d)                                                    \
        do {                                                                 \
            int _r = (r);                                                    \
            if ((unsigned)_r < (unsigned)HW_) {                              \
                const float* _p = img + _r * HW_ + 4 * qc;                   \
                float4 _v = *(const float4*)_p;                              \
                d[1] = _v.x; d[2] = _v.y; d[3] = _v.z; d[4] = _v.w;          \
                d[0] = (qc > 0)  ? _p[-1] : 0.f;                             \
                d[5] = (qc < 23) ? _p[4]  : 0.f;                             \
            } else {                                                         \
                d[0] = d[1] = d[2] = d[3] = d[4] = d[5] = 0.f;               \
            }                                                                \
        } while (0)

    LOADROW(r0 - 1, A);
    LOADROW(r0,     Bv);

    #pragma unroll
    for (int i = 0; i < 12; ++i) {
        int r = r0 + i;
        LOADROW(r + 1, Cv);
        float4 o;
        o.x = bs; o.y = bs; o.z = bs; o.w = bs;
        #pragma unroll
        for (int j = 0; j < 3; ++j) {
            o.x += A[j]  * w[j] + Bv[j]  * w[3+j] + Cv[j]  * w[6+j];
            o.y += A[j+1]* w[j] + Bv[j+1]* w[3+j] + Cv[j+1]* w[6+j];
            o.z += A[j+2]* w[j] + Bv[j+2]* w[3+j] + Cv[j+2]* w[6+j];
            o.w += A[j+3]* w[j] + Bv[j+3]* w[3+j] + Cv[j+3]* w[6+j];
        }
        dst[r * 24 + qc] = o;
        #pragma unroll
        for (int j = 0; j < 6; ++j) { A[j] = Bv[j]; Bv[j] = Cv[j]; }
    }
    #undef LOADROW
}

// ---------------------------------------------------------------------------
extern "C" void kernel_launch(void* const* d_in, const int* in_sizes, int n_in,
                              void* d_out, int out_size, void* d_ws, size_t ws_size,
                              hipStream_t stream) {
    const float* x     = (const float*)d_in[0];
    const float* dyn_w = (const float*)d_in[1];
    const float* dyn_b = (const float*)d_in[2];
    const float* w1    = (const float*)d_in[3];
    const float* bn_g  = (const float*)d_in[4];
    const float* bn_b  = (const float*)d_in[5];
    const float* bn_m  = (const float*)d_in[6];
    const float* bn_v  = (const float*)d_in[7];
    const float* w2    = (const float*)d_in[8];
    const float* b2    = (const float*)d_in[9];
    float* out = (float*)d_out;

    float* ws = (float*)d_ws;
    float* pooled = ws;                        // [B*C, 9]  = 73728 floats
    float* weight = ws + (size_t)B_ * C_ * 9;  // [B*C, 9]  = 73728 floats
    float* bias   = weight + (size_t)B_ * C_ * 9;  // [B*C] = 8192 floats

    pool_kernel<<<B_ * C_ * 3, 256, 0, stream>>>(x, pooled);
    proj_kernel<<<B_, 256, 0, stream>>>(pooled, dyn_w, dyn_b, w1, bn_g, bn_b,
                                        bn_m, bn_v, w2, b2, weight, bias);
    dwconv_kernel<<<B_ * C_, 192, 0, stream>>>(x, weight, bias, out);
}